// Round 1
// baseline (129.505 us; speedup 1.0000x reference)
//
#include <hip/hip_runtime.h>

#define NIN 96
#define NOUT 192
#define BATCH 2
#define NVOX (NIN * NIN * NIN)

__device__ __forceinline__ float2 f2_add(float2 a, float2 b) {
    return make_float2(a.x + b.x, a.y + b.y);
}
__device__ __forceinline__ float2 f2_scale(float2 a, float s) {
    return make_float2(a.x * s, a.y * s);
}

__global__ __launch_bounds__(256) void resize_zoom2_kernel(
        const float* __restrict__ in, float* __restrict__ out) {
    int idx = blockIdx.x * blockDim.x + threadIdx.x;
    // grid sized exactly: BATCH*NVOX = 1769472 = 6912 * 256, no bounds check needed
    int x = idx % NIN;
    int t = idx / NIN;
    int y = t % NIN;
    t /= NIN;
    int z = t % NIN;
    int b = t / NIN;

    int x1 = min(x + 1, NIN - 1);
    int y1 = min(y + 1, NIN - 1);
    int z1 = min(z + 1, NIN - 1);

    const float* vb = in + (size_t)b * (NVOX * 2);

    size_t r00 = (((size_t)z  * NIN + y ) * NIN) * 2;
    size_t r01 = (((size_t)z  * NIN + y1) * NIN) * 2;
    size_t r10 = (((size_t)z1 * NIN + y ) * NIN) * 2;
    size_t r11 = (((size_t)z1 * NIN + y1) * NIN) * 2;

    float2 v000 = *(const float2*)(vb + r00 + (size_t)x  * 2);
    float2 v001 = *(const float2*)(vb + r00 + (size_t)x1 * 2);
    float2 v010 = *(const float2*)(vb + r01 + (size_t)x  * 2);
    float2 v011 = *(const float2*)(vb + r01 + (size_t)x1 * 2);
    float2 v100 = *(const float2*)(vb + r10 + (size_t)x  * 2);
    float2 v101 = *(const float2*)(vb + r10 + (size_t)x1 * 2);
    float2 v110 = *(const float2*)(vb + r11 + (size_t)x  * 2);
    float2 v111 = *(const float2*)(vb + r11 + (size_t)x1 * 2);

    // 2x2x2 output block values (even/odd per dim)
    // even index -> weight (1,0); odd index -> (0.5,0.5), clamp handled by x1/y1/z1
    float2 e_ee = v000;                                             // z even, y even, x even
    float2 o_ee = f2_scale(f2_add(v000, v001), 0.5f);               // z even, y even, x odd
    float2 e_oe = f2_scale(f2_add(v000, v010), 0.5f);               // z even, y odd,  x even
    float2 o_oe = f2_scale(f2_add(f2_add(v000, v001), f2_add(v010, v011)), 0.25f);

    float2 e_ez = f2_scale(f2_add(v000, v100), 0.5f);               // z odd, y even, x even
    float2 o_ez = f2_scale(f2_add(f2_add(v000, v001), f2_add(v100, v101)), 0.25f);
    float2 e_oz = f2_scale(f2_add(f2_add(v000, v010), f2_add(v100, v110)), 0.25f);
    float2 o_oz = f2_scale(
        f2_add(f2_add(f2_add(v000, v001), f2_add(v010, v011)),
               f2_add(f2_add(v100, v101), f2_add(v110, v111))), 0.125f);

    float* ob = out + (size_t)b * ((size_t)NOUT * NOUT * NOUT * 2);
    int xo = 2 * x, yo = 2 * y, zo = 2 * z;
    size_t q = (((size_t)zo * NOUT + yo) * NOUT + xo) * 2;
    const size_t rowStride   = (size_t)NOUT * 2;          // one y row
    const size_t planeStride = (size_t)NOUT * NOUT * 2;   // one z plane

    *(float4*)(ob + q)                            = make_float4(e_ee.x, e_ee.y, o_ee.x, o_ee.y);
    *(float4*)(ob + q + rowStride)                = make_float4(e_oe.x, e_oe.y, o_oe.x, o_oe.y);
    *(float4*)(ob + q + planeStride)              = make_float4(e_ez.x, e_ez.y, o_ez.x, o_ez.y);
    *(float4*)(ob + q + planeStride + rowStride)  = make_float4(e_oz.x, e_oz.y, o_oz.x, o_oz.y);
}

extern "C" void kernel_launch(void* const* d_in, const int* in_sizes, int n_in,
                              void* d_out, int out_size, void* d_ws, size_t ws_size,
                              hipStream_t stream) {
    const float* in = (const float*)d_in[0];
    float* out = (float*)d_out;
    const int total = BATCH * NVOX;          // 1769472
    const int block = 256;
    const int grid = total / block;          // 6912, exact
    resize_zoom2_kernel<<<grid, block, 0, stream>>>(in, out);
}

// Round 2
// 124.740 us; speedup vs baseline: 1.0382x; 1.0382x over previous
//
#include <hip/hip_runtime.h>

constexpr int NIN  = 96;
constexpr int NOUT = 192;
constexpr int TZ = 4, TY = 4;          // input tile extents (z,y), full x
constexpr int HZ = TZ + 1, HY = TY + 1, HX = NIN + 1;   // halo'd tile 5x5x97
constexpr int NT = NIN / TZ;           // 24 tiles per dim

__global__ __launch_bounds__(256) void resize_zoom2_tiled(
        const float* __restrict__ in, float* __restrict__ out) {
    __shared__ float2 S[HZ * HY * HX];   // 2425 float2 = 19400 B

    int bid = blockIdx.x;                // 0..1151
    int yt = bid % NT;
    int t  = bid / NT;
    int zt = t % NT;
    int b  = t / NT;
    int z0 = zt * TZ, y0 = yt * TY;

    const float2* vin = (const float2*)in + (size_t)b * ((size_t)NIN * NIN * NIN);

    // ---- stage input tile (with +1 halo, clamped) into LDS; coalesced along x
    for (int i = threadIdx.x; i < HZ * HY * HX; i += 256) {
        int xx = i % HX;
        int r  = i / HX;                 // 0..24
        int dy = r % HY;
        int dz = r / HY;
        int zi = min(z0 + dz, NIN - 1);
        int yi = min(y0 + dy, NIN - 1);
        int xi = min(xx, NIN - 1);
        S[i] = vin[((size_t)zi * NIN + yi) * NIN + xi];
    }
    __syncthreads();

    // ---- emit 8x8x96 float4 outputs; 24 per thread, each store instruction
    //      covers a contiguous 4KB span (768 float4/plane = 3 * 256)
    float4* vout = (float4*)out;
    int Zb = 2 * z0, Yb = 2 * y0;

    #pragma unroll 4
    for (int k = 0; k < 24; ++k) {
        int j  = threadIdx.x + k * 256;  // 0..6143
        int xp = j % NIN;                // x-pair index 0..95
        int r  = j / NIN;                // 0..63
        int yo = r & 7;
        int zo = r >> 3;
        // even parity -> neighbor = self (average is exact); odd -> next (clamped via halo)
        int zA = zo >> 1, zB = zA + (zo & 1);
        int yA = yo >> 1, yB = yA + (yo & 1);
        const float2* rowAA = S + (zA * HY + yA) * HX;
        const float2* rowAB = S + (zA * HY + yB) * HX;
        const float2* rowBA = S + (zB * HY + yA) * HX;
        const float2* rowBB = S + (zB * HY + yB) * HX;
        float2 a0 = rowAA[xp],     a1 = rowAB[xp],     a2 = rowBA[xp],     a3 = rowBB[xp];
        float2 c0 = rowAA[xp + 1], c1 = rowAB[xp + 1], c2 = rowBA[xp + 1], c3 = rowBB[xp + 1];
        float sex = a0.x + a1.x + a2.x + a3.x;
        float sey = a0.y + a1.y + a2.y + a3.y;
        float sox = c0.x + c1.x + c2.x + c3.x;
        float soy = c0.y + c1.y + c2.y + c3.y;
        float4 v = make_float4(0.25f * sex, 0.25f * sey,
                               0.125f * (sex + sox), 0.125f * (sey + soy));
        size_t o4 = (((size_t)(b * NOUT + (Zb + zo))) * NOUT + (Yb + yo)) * (NOUT / 2) + xp;
        vout[o4] = v;
    }
}

extern "C" void kernel_launch(void* const* d_in, const int* in_sizes, int n_in,
                              void* d_out, int out_size, void* d_ws, size_t ws_size,
                              hipStream_t stream) {
    const float* in = (const float*)d_in[0];
    float* out = (float*)d_out;
    const int grid = 2 * NT * NT;        // 1152 blocks
    resize_zoom2_tiled<<<grid, 256, 0, stream>>>(in, out);
}

// Round 3
// 122.886 us; speedup vs baseline: 1.0539x; 1.0151x over previous
//
#include <hip/hip_runtime.h>

constexpr int NIN = 96, NOUT = 192;
constexpr int TZ = 2, TY = 4;              // input tile (z,y), full x
constexpr int HZ = TZ + 1, HY = TY + 1;    // 3, 5 (with +1 halo)
constexpr int ROWS = HZ * HY;              // 15 staged rows
constexpr int HXP = 98;                    // padded row length in float2 (784 B, 16B-aligned)
constexpr int F4R = NIN / 2;               // 48 float4 per input row
constexpr int NTZ = NIN / TZ, NTY = NIN / TY;  // 48, 24

__global__ __launch_bounds__(192) void resize_zoom2_v3(
        const float* __restrict__ in, float* __restrict__ out) {
    __shared__ __align__(16) float2 S[ROWS * HXP];   // 11760 B

    const int bid = blockIdx.x;
    const int yt = bid % NTY;
    const int tt = bid / NTY;
    const int zt = tt % NTZ;
    const int b  = tt / NTZ;
    const int z0 = zt * TZ, y0 = yt * TY;

    const float* vb = in + (size_t)b * ((size_t)NIN * NIN * NIN * 2);
    const float4* vin4 = (const float4*)vb;

    // ---- stage 15 halo'd rows (clamped), float4-vectorized, coalesced
    for (int i = threadIdx.x; i < ROWS * F4R; i += 192) {
        int r = i / F4R, col = i - r * F4R;
        int zi = min(z0 + r / HY, NIN - 1);
        int yi = min(y0 + (r - (r / HY) * HY), NIN - 1);
        float4 v = vin4[(size_t)(zi * NIN + yi) * F4R + col];
        *(float4*)((float*)(S + r * HXP) + 4 * col) = v;
    }
    if (threadIdx.x < ROWS) {               // x halo element (clamp of x=96)
        int r = threadIdx.x;
        int zi = min(z0 + r / HY, NIN - 1);
        int yi = min(y0 + r % HY, NIN - 1);
        S[r * HXP + NIN] = ((const float2*)vb)[(size_t)(zi * NIN + yi) * NIN + (NIN - 1)];
    }
    __syncthreads();

    // ---- compute: thread owns fixed (yhalf, xp); rolls along z carrying plane sums
    const int xp = threadIdx.x % NIN;       // 0..95  (output x-pair)
    const int yh = threadIdx.x / NIN;       // 0..1
    float4* vout = (float4*)out;
    constexpr size_t ZSTR = (size_t)NOUT * (NOUT / 2);   // float4 per output z-plane
    // float4 index of (zo=0, yo=yh, xp); across threads this is base + tid (contiguous)
    size_t ob = ((size_t)(b * NOUT + 2 * z0) * NOUT + (2 * y0 + yh)) * (NOUT / 2) + xp;

    #pragma unroll
    for (int y2 = 0; y2 < TY; ++y2) {
        const int yo = 2 * y2 + yh;
        const int yA = yo >> 1, yB = yA + (yo & 1);
        const float2* pA = S + yA * HXP;    // plane stride = HY*HXP
        const float2* pB = S + yB * HXP;

        float2 aA = pA[xp],     aB = pB[xp];
        float2 cA = pA[xp + 1], cB = pB[xp + 1];
        float sy_x  = aA.x + aB.x, sy_y  = aA.y + aB.y;   // plane-k y-sum at x
        float syc_x = cA.x + cB.x, syc_y = cA.y + cB.y;   // plane-k y-sum at x+1
        size_t o = ob + (size_t)y2 * NOUT;  // +2 output rows per y2

        #pragma unroll
        for (int k = 0; k < TZ; ++k) {
            const float2* qA = pA + (k + 1) * HY * HXP;
            const float2* qB = pB + (k + 1) * HY * HXP;
            float2 bA = qA[xp],     bB = qB[xp];
            float2 dA = qA[xp + 1], dB = qB[xp + 1];
            float ty_x  = bA.x + bB.x, ty_y  = bA.y + bB.y;  // plane-(k+1) sums
            float tyc_x = dA.x + dB.x, tyc_y = dA.y + dB.y;

            // zo = 2k (even z): plane k only
            vout[o + (size_t)(2 * k) * ZSTR] =
                make_float4(0.5f * sy_x, 0.5f * sy_y,
                            0.25f * (sy_x + syc_x), 0.25f * (sy_y + syc_y));
            // zo = 2k+1 (odd z): planes k and k+1
            float ux = sy_x + ty_x, uy = sy_y + ty_y;
            float vx = ux + syc_x + tyc_x, vy = uy + syc_y + tyc_y;
            vout[o + (size_t)(2 * k + 1) * ZSTR] =
                make_float4(0.25f * ux, 0.25f * uy, 0.125f * vx, 0.125f * vy);

            sy_x = ty_x; sy_y = ty_y; syc_x = tyc_x; syc_y = tyc_y;
        }
    }
}

extern "C" void kernel_launch(void* const* d_in, const int* in_sizes, int n_in,
                              void* d_out, int out_size, void* d_ws, size_t ws_size,
                              hipStream_t stream) {
    const float* in = (const float*)d_in[0];
    float* out = (float*)d_out;
    const int grid = 2 * NTZ * NTY;   // 2304 blocks
    resize_zoom2_v3<<<grid, 192, 0, stream>>>(in, out);
}